// Round 1
// baseline (1220.739 us; speedup 1.0000x reference)
//
#include <hip/hip_runtime.h>

// ---------------------------------------------------------------------------
// GINEdge: 3-layer GIN (sum agg) + per-layer edge MLP scoring.
// Key transform: relu([h_s,h_d]@W1+b1)@W2 == relu(P1[s]+P2[d])@W2 with
//   P1 = h@W1[:64] + b1, P2 = h@W1[64:]  (per-node projections).
// segment_sum via per-call CSR build (no float atomics).
// ---------------------------------------------------------------------------

#define BN_EPS 1e-5f

__global__ __launch_bounds__(256) void hist_kernel(const int* __restrict__ dst,
                                                   int* __restrict__ deg, int E) {
  int i = blockIdx.x * blockDim.x + threadIdx.x;
  int stride = gridDim.x * blockDim.x;
  for (; i < E; i += stride) atomicAdd(&deg[dst[i]], 1);
}

__global__ __launch_bounds__(1024) void scan_kernel(const int* __restrict__ deg,
                                                    int* __restrict__ rowstart,
                                                    int* __restrict__ cursor, int N) {
  __shared__ int s[1024];
  __shared__ int carry_s;
  int tid = threadIdx.x;
  if (tid == 0) carry_s = 0;
  __syncthreads();
  for (int base = 0; base < N; base += 1024) {
    int i = base + tid;
    int v = (i < N) ? deg[i] : 0;
    s[tid] = v;
    __syncthreads();
    for (int off = 1; off < 1024; off <<= 1) {
      int t = (tid >= off) ? s[tid - off] : 0;
      __syncthreads();
      s[tid] += t;
      __syncthreads();
    }
    int excl = s[tid] - v + carry_s;
    if (i < N) { rowstart[i] = excl; cursor[i] = excl; }
    __syncthreads();
    if (tid == 1023) carry_s += s[1023];
    __syncthreads();
  }
  if (tid == 0) rowstart[N] = carry_s;
}

__global__ __launch_bounds__(256) void fill_kernel(const int* __restrict__ src,
                                                   const int* __restrict__ dst,
                                                   int* __restrict__ cursor,
                                                   int* __restrict__ eidx, int E) {
  int i = blockIdx.x * blockDim.x + threadIdx.x;
  int stride = gridDim.x * blockDim.x;
  for (; i < E; i += stride) {
    int p = atomicAdd(&cursor[dst[i]], 1);
    eidx[p] = src[i];
  }
}

// z[v] = hn[v] + sum_{u in in-neighbors(v)} hn[u].  One wave per node (64 feats).
__global__ __launch_bounds__(256) void agg_kernel(const float* __restrict__ hn,
                                                  const int* __restrict__ rowstart,
                                                  const int* __restrict__ eidx,
                                                  float* __restrict__ z, int N) {
  int lane = threadIdx.x & 63;
  int v = blockIdx.x * 4 + (threadIdx.x >> 6);
  if (v >= N) return;
  float acc = hn[(size_t)v * 64 + lane];
  int p0 = rowstart[v], p1 = rowstart[v + 1];
  for (int p = p0; p < p1; ++p) {
    int u = eidx[p];  // wave-uniform -> scalar load
    acc += hn[(size_t)u * 64 + lane];
  }
  z[(size_t)v * 64 + lane] = acc;
}

// out[n][f] = bias[f] + sum_k T(in[n][k]) * W[k][f]
// T = identity, or (if stats_in) relu(bn(x)) with bn from stats_in/g_in/b_in.
// Optionally accumulates per-feature column sum/sumsq of out into stats_out.
__global__ __launch_bounds__(256) void gemm64_kernel(
    const float* __restrict__ in, const float* __restrict__ W,
    const float* __restrict__ bias, const float* __restrict__ stats_in,
    const float* __restrict__ g_in, const float* __restrict__ b_in,
    float* __restrict__ out, float* __restrict__ stats_out, int N) {
  __shared__ float sW[64][64];
  __shared__ float sx[32][64];
  __shared__ float red[2][4][64];
  int tid = threadIdx.x;
  int lane = tid & 63, w = tid >> 6;
  int n0 = blockIdx.x * 32;
#pragma unroll
  for (int r = 0; r < 16; ++r) {
    int idx = r * 256 + tid;
    sW[idx >> 6][idx & 63] = W[idx];
  }
  float sc = 1.f, sh = 0.f;
  if (stats_in) {
    float invN = 1.0f / (float)N;
    float m = stats_in[lane] * invN;
    float var = stats_in[64 + lane] * invN - m * m;
    sc = g_in[lane] * rsqrtf(var + BN_EPS);
    sh = b_in[lane] - m * sc;
  }
#pragma unroll
  for (int r = 0; r < 8; ++r) {
    int idx = r * 256 + tid;       // (idx&63)==lane since 256%64==0
    int n = n0 + (idx >> 6);
    float x = (n < N) ? in[(size_t)n * 64 + lane] : 0.f;
    if (stats_in) x = fmaxf(x * sc + sh, 0.f);
    sx[idx >> 6][lane] = x;
  }
  __syncthreads();
  float acc[8];
  float bz = bias ? bias[lane] : 0.f;
#pragma unroll
  for (int j = 0; j < 8; ++j) acc[j] = bz;
  for (int k = 0; k < 64; ++k) {
    float wv = sW[k][lane];
#pragma unroll
    for (int j = 0; j < 8; ++j) acc[j] = fmaf(sx[w * 8 + j][k], wv, acc[j]);
  }
  float ps = 0.f, pq = 0.f;
#pragma unroll
  for (int j = 0; j < 8; ++j) {
    int n = n0 + w * 8 + j;
    if (n < N) {
      out[(size_t)n * 64 + lane] = acc[j];
      ps += acc[j];
      pq += acc[j] * acc[j];
    }
  }
  if (stats_out) {
    red[0][w][lane] = ps;
    red[1][w][lane] = pq;
    __syncthreads();
    if (w == 0) {
      float s = red[0][0][lane] + red[0][1][lane] + red[0][2][lane] + red[0][3][lane];
      float q = red[1][0][lane] + red[1][1][lane] + red[1][2][lane] + red[1][3][lane];
      atomicAdd(&stats_out[lane], s);
      atomicAdd(&stats_out[64 + lane], q);
    }
  }
}

// P1 = hn @ W1[0:64] + b1 ; P2 = hn @ W1[64:128]   (W1 is [128][64] row-major)
__global__ __launch_bounds__(256) void proj_kernel(const float* __restrict__ hn,
                                                   const float* __restrict__ W1,
                                                   const float* __restrict__ b1,
                                                   float* __restrict__ P1,
                                                   float* __restrict__ P2, int N) {
  __shared__ float sWa[64][64];
  __shared__ float sWb[64][64];
  __shared__ float sx[32][64];
  int tid = threadIdx.x, lane = tid & 63, w = tid >> 6;
  int n0 = blockIdx.x * 32;
#pragma unroll
  for (int r = 0; r < 16; ++r) {
    int idx = r * 256 + tid;
    sWa[idx >> 6][idx & 63] = W1[idx];
    sWb[idx >> 6][idx & 63] = W1[4096 + idx];
  }
#pragma unroll
  for (int r = 0; r < 8; ++r) {
    int idx = r * 256 + tid;
    int n = n0 + (idx >> 6);
    sx[idx >> 6][lane] = (n < N) ? hn[(size_t)n * 64 + lane] : 0.f;
  }
  __syncthreads();
  float a1[8], a2[8];
  float bz = b1[lane];
#pragma unroll
  for (int j = 0; j < 8; ++j) { a1[j] = bz; a2[j] = 0.f; }
  for (int k = 0; k < 64; ++k) {
    float wa = sWa[k][lane];
    float wb = sWb[k][lane];
#pragma unroll
    for (int j = 0; j < 8; ++j) {
      float x = sx[w * 8 + j][k];
      a1[j] = fmaf(x, wa, a1[j]);
      a2[j] = fmaf(x, wb, a2[j]);
    }
  }
#pragma unroll
  for (int j = 0; j < 8; ++j) {
    int n = n0 + w * 8 + j;
    if (n < N) {
      P1[(size_t)n * 64 + lane] = a1[j];
      P2[(size_t)n * 64 + lane] = a2[j];
    }
  }
}

// out = relu(bn(in)) elementwise; optionally accumulate col stats of out.
__global__ __launch_bounds__(256) void bnrelu_kernel(
    const float* __restrict__ in, const float* __restrict__ stats_in,
    const float* __restrict__ g_in, const float* __restrict__ b_in,
    float* __restrict__ out, float* __restrict__ stats_out, int N) {
  __shared__ float red[2][4][64];
  int tid = threadIdx.x;
  int lane = tid & 63, w = tid >> 6;
  float invN = 1.0f / (float)N;
  float m = stats_in[lane] * invN;
  float var = stats_in[64 + lane] * invN - m * m;
  float sc = g_in[lane] * rsqrtf(var + BN_EPS);
  float sh = b_in[lane] - m * sc;
  float ps = 0.f, pq = 0.f;
  int rows_per_grid = gridDim.x * (blockDim.x >> 6);
  for (int n = blockIdx.x * (blockDim.x >> 6) + w; n < N; n += rows_per_grid) {
    float x = fmaxf(in[(size_t)n * 64 + lane] * sc + sh, 0.f);
    out[(size_t)n * 64 + lane] = x;
    ps += x;
    pq += x * x;
  }
  if (stats_out) {
    red[0][w][lane] = ps;
    red[1][w][lane] = pq;
    __syncthreads();
    if (w == 0) {
      float s = red[0][0][lane] + red[0][1][lane] + red[0][2][lane] + red[0][3][lane];
      float q = red[1][0][lane] + red[1][1][lane] + red[1][2][lane] + red[1][3][lane];
      atomicAdd(&stats_out[lane], s);
      atomicAdd(&stats_out[64 + lane], q);
    }
  }
}

// score[e] (+)= relu(P1[src]+P2[dst]) @ W2 + b2.  16 lanes per edge, float4 each.
__global__ __launch_bounds__(256) void edge_score_kernel(
    const float* __restrict__ P1, const float* __restrict__ P2,
    const int* __restrict__ src, const int* __restrict__ dst,
    const float* __restrict__ W2, const float* __restrict__ b2,
    float* __restrict__ out, int E, int first) {
  int t = blockIdx.x * blockDim.x + threadIdx.x;
  int e = t >> 4;
  if (e >= E) return;
  int sub = t & 15;
  int s = src[e], d = dst[e];
  const float4 a = *reinterpret_cast<const float4*>(P1 + (size_t)s * 64 + sub * 4);
  const float4 b = *reinterpret_cast<const float4*>(P2 + (size_t)d * 64 + sub * 4);
  float v0 = fmaxf(a.x + b.x, 0.f);
  float v1 = fmaxf(a.y + b.y, 0.f);
  float v2 = fmaxf(a.z + b.z, 0.f);
  float v3 = fmaxf(a.w + b.w, 0.f);
  int j0 = sub * 4;
  float p0 = v0 * W2[(j0 + 0) * 2] + v1 * W2[(j0 + 1) * 2] +
             v2 * W2[(j0 + 2) * 2] + v3 * W2[(j0 + 3) * 2];
  float p1 = v0 * W2[(j0 + 0) * 2 + 1] + v1 * W2[(j0 + 1) * 2 + 1] +
             v2 * W2[(j0 + 2) * 2 + 1] + v3 * W2[(j0 + 3) * 2 + 1];
#pragma unroll
  for (int mm = 1; mm < 16; mm <<= 1) {
    p0 += __shfl_xor(p0, mm);
    p1 += __shfl_xor(p1, mm);
  }
  if (sub == 0) {
    float o0 = p0 + b2[0];
    float o1 = p1 + b2[1];
    if (!first) {
      o0 += out[(size_t)e * 2];
      o1 += out[(size_t)e * 2 + 1];
    }
    out[(size_t)e * 2] = o0;
    out[(size_t)e * 2 + 1] = o1;
  }
}

extern "C" void kernel_launch(void* const* d_in, const int* in_sizes, int n_in,
                              void* d_out, int out_size, void* d_ws, size_t ws_size,
                              hipStream_t stream) {
  const float* h          = (const float*)d_in[0];
  const int*   src        = (const int*)d_in[1];
  const int*   dst        = (const int*)d_in[2];
  const float* emb_W      = (const float*)d_in[3];
  const float* emb_b      = (const float*)d_in[4];
  const float* mlp_W1     = (const float*)d_in[5];
  const float* mlp_b1     = (const float*)d_in[6];
  const float* mlp_bn_g   = (const float*)d_in[7];
  const float* mlp_bn_b   = (const float*)d_in[8];
  const float* mlp_W2     = (const float*)d_in[9];
  const float* mlp_b2     = (const float*)d_in[10];
  const float* apply_bn_g = (const float*)d_in[11];
  const float* apply_bn_b = (const float*)d_in[12];
  const float* out_bn_g   = (const float*)d_in[13];
  const float* out_bn_b   = (const float*)d_in[14];
  const float* pred_W1    = (const float*)d_in[15];
  const float* pred_b1    = (const float*)d_in[16];
  const float* pred_W2    = (const float*)d_in[17];
  const float* pred_b2    = (const float*)d_in[18];

  const int N = in_sizes[0] / 64;
  const int E = in_sizes[1];
  const size_t NF = (size_t)N * 64;

  float* ws = (float*)d_ws;
  float* hn = ws;             // current node features
  float* zb = hn + NF;        // hn + agg
  float* z1 = zb + NF;        // also reused for t
  float* z2 = z1 + NF;
  float* P1 = z2 + NF;
  float* P2 = P1 + NF;
  int* eidx     = (int*)(P2 + NF);
  int* rowstart = eidx + E;            // N+1 (padded to N+64)
  int* cursor   = rowstart + (N + 64);
  int* deg      = cursor + (N + 64);
  float* stats  = (float*)(deg + (N + 64));  // 9 slots x [sum(64), sumsq(64)]

  size_t need = (size_t)((char*)(stats + 9 * 128) - (char*)d_ws);
  if (need > ws_size) return;  // insufficient workspace (shouldn't happen: ~81 MB)

  // zero deg + stats in one async memset (graph-capture safe)
  hipMemsetAsync(deg, 0, ((size_t)(N + 64) + 9 * 128) * sizeof(int), stream);

  const int gemmBlocks = (N + 31) / 32;
  const int edgeBlocks = (int)(((size_t)E * 16 + 255) / 256);

  // embedding: hn = h @ emb_W + emb_b
  gemm64_kernel<<<gemmBlocks, 256, 0, stream>>>(h, emb_W, emb_b, nullptr, nullptr,
                                                nullptr, hn, nullptr, N);
  // CSR build (by dst)
  hist_kernel<<<1024, 256, 0, stream>>>(dst, deg, E);
  scan_kernel<<<1, 1024, 0, stream>>>(deg, rowstart, cursor, N);
  fill_kernel<<<1024, 256, 0, stream>>>(src, dst, cursor, eidx, E);

  // layer-0 edge rep scoring
  proj_kernel<<<gemmBlocks, 256, 0, stream>>>(hn, pred_W1, pred_b1, P1, P2, N);
  edge_score_kernel<<<edgeBlocks, 256, 0, stream>>>(P1, P2, src, dst, pred_W2,
                                                    pred_b2, (float*)d_out, E, 1);

  for (int i = 0; i < 3; ++i) {
    float* st1 = stats + (size_t)(3 * i + 0) * 128;
    float* st2 = stats + (size_t)(3 * i + 1) * 128;
    float* st3 = stats + (size_t)(3 * i + 2) * 128;
    // z = hn + segment_sum(hn[src], dst)
    agg_kernel<<<(N + 3) / 4, 256, 0, stream>>>(hn, rowstart, eidx, zb, N);
    // z1 = z @ W1 + b1  (+ stats of z1)
    gemm64_kernel<<<gemmBlocks, 256, 0, stream>>>(zb, mlp_W1 + (size_t)i * 4096,
                                                  mlp_b1 + i * 64, nullptr, nullptr,
                                                  nullptr, z1, st1, N);
    // z2 = relu(bn(z1)) @ W2 + b2  (+ stats of z2)
    gemm64_kernel<<<gemmBlocks, 256, 0, stream>>>(z1, mlp_W2 + (size_t)i * 4096,
                                                  mlp_b2 + i * 64, st1,
                                                  mlp_bn_g + i * 64, mlp_bn_b + i * 64,
                                                  z2, st2, N);
    // t = relu(bn_apply(z2))  (+ stats of t), t stored in z1 buffer
    bnrelu_kernel<<<784, 256, 0, stream>>>(z2, st2, apply_bn_g + i * 64,
                                           apply_bn_b + i * 64, z1, st3, N);
    // hn = relu(bn_out(t))
    bnrelu_kernel<<<784, 256, 0, stream>>>(z1, st3, out_bn_g + i * 64,
                                           out_bn_b + i * 64, hn, nullptr, N);
    // edge rep (i+1) scoring
    proj_kernel<<<gemmBlocks, 256, 0, stream>>>(hn, pred_W1 + (size_t)(i + 1) * 8192,
                                                pred_b1 + (i + 1) * 64, P1, P2, N);
    edge_score_kernel<<<edgeBlocks, 256, 0, stream>>>(P1, P2, src, dst,
                                                      pred_W2 + (i + 1) * 128,
                                                      pred_b2 + (i + 1) * 2,
                                                      (float*)d_out, E, 0);
  }
}

// Round 3
// 1033.967 us; speedup vs baseline: 1.1806x; 1.1806x over previous
//
#include <hip/hip_runtime.h>
#include <hip/hip_bf16.h>

// ---------------------------------------------------------------------------
// GINEdge: 3-layer GIN (sum agg) + per-layer edge MLP scoring.
//   relu([h_s,h_d]@W1+b1)@W2 == relu(P1[s]+P2[d])@W2,
//   P1 = h@W1[:64] + b1, P2 = h@W1[64:]  (per-node projections).
// Gather payloads (P1/P2, neighbor hn) stored bf16 -> halves the dominant
// L3-gather traffic; all accumulation in f32.
// segment_sum via per-call CSR build (no float atomics).
// ---------------------------------------------------------------------------

#define BN_EPS 1e-5f

__global__ __launch_bounds__(256) void hist_kernel(const int* __restrict__ dst,
                                                   int* __restrict__ deg, int E) {
  int i = blockIdx.x * blockDim.x + threadIdx.x;
  int stride = gridDim.x * blockDim.x;
  for (; i < E; i += stride) atomicAdd(&deg[dst[i]], 1);
}

// hierarchical scan, step 1: per-block (1024 elems) exclusive scan + block sum
__global__ __launch_bounds__(256) void scan1_kernel(const int* __restrict__ deg,
                                                    int* __restrict__ rowstart,
                                                    int* __restrict__ partials, int N) {
  __shared__ int wsum[4];
  int tid = threadIdx.x;
  int lane = tid & 63, w = tid >> 6;
  int base = blockIdx.x * 1024 + tid * 4;
  int d0 = 0, d1 = 0, d2 = 0, d3 = 0;
  if (base + 3 < N) {
    int4 v = *reinterpret_cast<const int4*>(deg + base);
    d0 = v.x; d1 = v.y; d2 = v.z; d3 = v.w;
  } else {
    if (base + 0 < N) d0 = deg[base + 0];
    if (base + 1 < N) d1 = deg[base + 1];
    if (base + 2 < N) d2 = deg[base + 2];
  }
  int t0 = d0, t1 = t0 + d1, t2 = t1 + d2, t3 = t2 + d3;
  int tot = t3;
  int inc = tot;
#pragma unroll
  for (int off = 1; off < 64; off <<= 1) {
    int v = __shfl_up(inc, off);
    if (lane >= off) inc += v;
  }
  if (lane == 63) wsum[w] = inc;
  __syncthreads();
  int woff = 0;
  for (int k = 0; k < w; ++k) woff += wsum[k];
  int excl = woff + inc - tot;
  if (base + 0 < N) rowstart[base + 0] = excl;
  if (base + 1 < N) rowstart[base + 1] = excl + t0;
  if (base + 2 < N) rowstart[base + 2] = excl + t1;
  if (base + 3 < N) rowstart[base + 3] = excl + t2;
  if (tid == 255) partials[blockIdx.x] = excl + t3;
}

// step 2: exclusive-scan the (<=64) block partials; write total to rowstart[N]
__global__ __launch_bounds__(64) void scan2_kernel(int* __restrict__ partials,
                                                   int* __restrict__ rowstart_end,
                                                   int NB) {
  int lane = threadIdx.x;
  int v = (lane < NB) ? partials[lane] : 0;
  int inc = v;
#pragma unroll
  for (int off = 1; off < 64; off <<= 1) {
    int t = __shfl_up(inc, off);
    if (lane >= off) inc += t;
  }
  if (lane < NB) partials[lane] = inc - v;
  if (lane == 63) *rowstart_end = inc;
}

// step 3: add block offsets, mirror into cursor
__global__ __launch_bounds__(256) void scan3_kernel(const int* __restrict__ partials,
                                                    int* __restrict__ rowstart,
                                                    int* __restrict__ cursor, int N) {
  int off = partials[blockIdx.x];
  int base = blockIdx.x * 1024 + threadIdx.x * 4;
#pragma unroll
  for (int k = 0; k < 4; ++k) {
    int i = base + k;
    if (i < N) {
      int r = rowstart[i] + off;
      rowstart[i] = r;
      cursor[i] = r;
    }
  }
}

__global__ __launch_bounds__(256) void fill_kernel(const int* __restrict__ src,
                                                   const int* __restrict__ dst,
                                                   int* __restrict__ cursor,
                                                   int* __restrict__ eidx, int E) {
  int i = blockIdx.x * blockDim.x + threadIdx.x;
  int stride = gridDim.x * blockDim.x;
  for (; i < E; i += stride) {
    int p = atomicAdd(&cursor[dst[i]], 1);
    eidx[p] = src[i];
  }
}

// z[v] = hn[v] + sum_{u->v} hnb[u] (bf16 neighbor rows, f32 accum). 1 wave/node.
__global__ __launch_bounds__(256) void agg_kernel(const float* __restrict__ hn,
                                                  const ushort* __restrict__ hnb,
                                                  const int* __restrict__ rowstart,
                                                  const int* __restrict__ eidx,
                                                  float* __restrict__ z, int N) {
  int lane = threadIdx.x & 63;
  int v = blockIdx.x * 4 + (threadIdx.x >> 6);
  if (v >= N) return;
  float acc = hn[(size_t)v * 64 + lane];
  int p0 = rowstart[v], p1 = rowstart[v + 1];
  for (int p = p0; p < p1; ++p) {
    int u = eidx[p];  // wave-uniform -> scalar load
    acc += __uint_as_float(((unsigned)hnb[(size_t)u * 64 + lane]) << 16);
  }
  z[(size_t)v * 64 + lane] = acc;
}

// out[n][f] = bias[f] + sum_k T(in[n][k]) * W[k][f]
// T = identity, or (if stats_in) relu(bn(x)). Optional col sum/sumsq of out
// into stats_out; optional bf16 mirror of out into out_bf.
__global__ __launch_bounds__(256) void gemm64_kernel(
    const float* __restrict__ in, const float* __restrict__ W,
    const float* __restrict__ bias, const float* __restrict__ stats_in,
    const float* __restrict__ g_in, const float* __restrict__ b_in,
    float* __restrict__ out, float* __restrict__ stats_out,
    __hip_bfloat16* __restrict__ out_bf, int N) {
  __shared__ float sW[64][64];
  __shared__ float sx[32][64];
  __shared__ float red[2][4][64];
  int tid = threadIdx.x;
  int lane = tid & 63, w = tid >> 6;
  int n0 = blockIdx.x * 32;
#pragma unroll
  for (int r = 0; r < 16; ++r) {
    int idx = r * 256 + tid;
    sW[idx >> 6][idx & 63] = W[idx];
  }
  float sc = 1.f, sh = 0.f;
  if (stats_in) {
    float invN = 1.0f / (float)N;
    float m = stats_in[lane] * invN;
    float var = stats_in[64 + lane] * invN - m * m;
    sc = g_in[lane] * rsqrtf(var + BN_EPS);
    sh = b_in[lane] - m * sc;
  }
#pragma unroll
  for (int r = 0; r < 8; ++r) {
    int idx = r * 256 + tid;  // (idx&63)==lane since 256%64==0
    int n = n0 + (idx >> 6);
    float x = (n < N) ? in[(size_t)n * 64 + lane] : 0.f;
    if (stats_in) x = fmaxf(x * sc + sh, 0.f);
    sx[idx >> 6][lane] = x;
  }
  __syncthreads();
  float acc[8];
  float bz = bias ? bias[lane] : 0.f;
#pragma unroll
  for (int j = 0; j < 8; ++j) acc[j] = bz;
  for (int k = 0; k < 64; ++k) {
    float wv = sW[k][lane];
#pragma unroll
    for (int j = 0; j < 8; ++j) acc[j] = fmaf(sx[w * 8 + j][k], wv, acc[j]);
  }
  float ps = 0.f, pq = 0.f;
#pragma unroll
  for (int j = 0; j < 8; ++j) {
    int n = n0 + w * 8 + j;
    if (n < N) {
      out[(size_t)n * 64 + lane] = acc[j];
      if (out_bf) out_bf[(size_t)n * 64 + lane] = __float2bfloat16(acc[j]);
      ps += acc[j];
      pq += acc[j] * acc[j];
    }
  }
  if (stats_out) {
    red[0][w][lane] = ps;
    red[1][w][lane] = pq;
    __syncthreads();
    if (w == 0) {
      float s = red[0][0][lane] + red[0][1][lane] + red[0][2][lane] + red[0][3][lane];
      float q = red[1][0][lane] + red[1][1][lane] + red[1][2][lane] + red[1][3][lane];
      atomicAdd(&stats_out[lane], s);
      atomicAdd(&stats_out[64 + lane], q);
    }
  }
}

// P1 = hn @ W1[0:64] + b1 ; P2 = hn @ W1[64:128]  -> bf16
__global__ __launch_bounds__(256) void proj_kernel(const float* __restrict__ hn,
                                                   const float* __restrict__ W1,
                                                   const float* __restrict__ b1,
                                                   __hip_bfloat16* __restrict__ P1,
                                                   __hip_bfloat16* __restrict__ P2,
                                                   int N) {
  __shared__ float sWa[64][64];
  __shared__ float sWb[64][64];
  __shared__ float sx[32][64];
  int tid = threadIdx.x, lane = tid & 63, w = tid >> 6;
  int n0 = blockIdx.x * 32;
#pragma unroll
  for (int r = 0; r < 16; ++r) {
    int idx = r * 256 + tid;
    sWa[idx >> 6][idx & 63] = W1[idx];
    sWb[idx >> 6][idx & 63] = W1[4096 + idx];
  }
#pragma unroll
  for (int r = 0; r < 8; ++r) {
    int idx = r * 256 + tid;
    int n = n0 + (idx >> 6);
    sx[idx >> 6][lane] = (n < N) ? hn[(size_t)n * 64 + lane] : 0.f;
  }
  __syncthreads();
  float a1[8], a2[8];
  float bz = b1[lane];
#pragma unroll
  for (int j = 0; j < 8; ++j) { a1[j] = bz; a2[j] = 0.f; }
  for (int k = 0; k < 64; ++k) {
    float wa = sWa[k][lane];
    float wb = sWb[k][lane];
#pragma unroll
    for (int j = 0; j < 8; ++j) {
      float x = sx[w * 8 + j][k];
      a1[j] = fmaf(x, wa, a1[j]);
      a2[j] = fmaf(x, wb, a2[j]);
    }
  }
#pragma unroll
  for (int j = 0; j < 8; ++j) {
    int n = n0 + w * 8 + j;
    if (n < N) {
      P1[(size_t)n * 64 + lane] = __float2bfloat16(a1[j]);
      P2[(size_t)n * 64 + lane] = __float2bfloat16(a2[j]);
    }
  }
}

// out = relu(bn(in)); optional col stats of out; optional bf16 mirror.
__global__ __launch_bounds__(256) void bnrelu_kernel(
    const float* __restrict__ in, const float* __restrict__ stats_in,
    const float* __restrict__ g_in, const float* __restrict__ b_in,
    float* __restrict__ out, float* __restrict__ stats_out,
    __hip_bfloat16* __restrict__ out_bf, int N) {
  __shared__ float red[2][4][64];
  int tid = threadIdx.x;
  int lane = tid & 63, w = tid >> 6;
  float invN = 1.0f / (float)N;
  float m = stats_in[lane] * invN;
  float var = stats_in[64 + lane] * invN - m * m;
  float sc = g_in[lane] * rsqrtf(var + BN_EPS);
  float sh = b_in[lane] - m * sc;
  float ps = 0.f, pq = 0.f;
  int rows_per_grid = gridDim.x * (blockDim.x >> 6);
  for (int n = blockIdx.x * (blockDim.x >> 6) + w; n < N; n += rows_per_grid) {
    float x = fmaxf(in[(size_t)n * 64 + lane] * sc + sh, 0.f);
    out[(size_t)n * 64 + lane] = x;
    if (out_bf) out_bf[(size_t)n * 64 + lane] = __float2bfloat16(x);
    ps += x;
    pq += x * x;
  }
  if (stats_out) {
    red[0][w][lane] = ps;
    red[1][w][lane] = pq;
    __syncthreads();
    if (w == 0) {
      float s = red[0][0][lane] + red[0][1][lane] + red[0][2][lane] + red[0][3][lane];
      float q = red[1][0][lane] + red[1][1][lane] + red[1][2][lane] + red[1][3][lane];
      atomicAdd(&stats_out[lane], s);
      atomicAdd(&stats_out[64 + lane], q);
    }
  }
}

// score[e] (+)= relu(P1[src]+P2[dst]) @ W2 + b2.  8 lanes/edge, 16B bf16 loads.
__global__ __launch_bounds__(256) void edge_score_kernel(
    const ushort* __restrict__ P1, const ushort* __restrict__ P2,
    const int* __restrict__ src, const int* __restrict__ dst,
    const float* __restrict__ W2, const float* __restrict__ b2,
    float* __restrict__ out, int E, int first) {
  __shared__ float sW2[128];
  int tid = threadIdx.x;
  if (tid < 128) sW2[tid] = W2[tid];
  __syncthreads();
  int t = blockIdx.x * blockDim.x + tid;
  int e = t >> 3;
  if (e >= E) return;
  int sub = t & 7;
  int s = src[e], d = dst[e];
  uint4 ua = *reinterpret_cast<const uint4*>(P1 + (size_t)s * 64 + sub * 8);
  uint4 ub = *reinterpret_cast<const uint4*>(P2 + (size_t)d * 64 + sub * 8);
  unsigned av[4] = {ua.x, ua.y, ua.z, ua.w};
  unsigned bv[4] = {ub.x, ub.y, ub.z, ub.w};
  const float* w = sW2 + sub * 16;
  float p0 = 0.f, p1 = 0.f;
#pragma unroll
  for (int k = 0; k < 4; ++k) {
    float a_lo = __uint_as_float(av[k] << 16);
    float a_hi = __uint_as_float(av[k] & 0xffff0000u);
    float b_lo = __uint_as_float(bv[k] << 16);
    float b_hi = __uint_as_float(bv[k] & 0xffff0000u);
    float v0 = fmaxf(a_lo + b_lo, 0.f);
    float v1 = fmaxf(a_hi + b_hi, 0.f);
    p0 = fmaf(v0, w[4 * k + 0], fmaf(v1, w[4 * k + 2], p0));
    p1 = fmaf(v0, w[4 * k + 1], fmaf(v1, w[4 * k + 3], p1));
  }
#pragma unroll
  for (int mm = 1; mm < 8; mm <<= 1) {
    p0 += __shfl_xor(p0, mm);
    p1 += __shfl_xor(p1, mm);
  }
  if (sub == 0) {
    float o0 = p0 + b2[0];
    float o1 = p1 + b2[1];
    if (!first) {
      o0 += out[(size_t)e * 2];
      o1 += out[(size_t)e * 2 + 1];
    }
    out[(size_t)e * 2] = o0;
    out[(size_t)e * 2 + 1] = o1;
  }
}

extern "C" void kernel_launch(void* const* d_in, const int* in_sizes, int n_in,
                              void* d_out, int out_size, void* d_ws, size_t ws_size,
                              hipStream_t stream) {
  const float* h          = (const float*)d_in[0];
  const int*   src        = (const int*)d_in[1];
  const int*   dst        = (const int*)d_in[2];
  const float* emb_W      = (const float*)d_in[3];
  const float* emb_b      = (const float*)d_in[4];
  const float* mlp_W1     = (const float*)d_in[5];
  const float* mlp_b1     = (const float*)d_in[6];
  const float* mlp_bn_g   = (const float*)d_in[7];
  const float* mlp_bn_b   = (const float*)d_in[8];
  const float* mlp_W2     = (const float*)d_in[9];
  const float* mlp_b2     = (const float*)d_in[10];
  const float* apply_bn_g = (const float*)d_in[11];
  const float* apply_bn_b = (const float*)d_in[12];
  const float* out_bn_g   = (const float*)d_in[13];
  const float* out_bn_b   = (const float*)d_in[14];
  const float* pred_W1    = (const float*)d_in[15];
  const float* pred_b1    = (const float*)d_in[16];
  const float* pred_W2    = (const float*)d_in[17];
  const float* pred_b2    = (const float*)d_in[18];

  const int N = in_sizes[0] / 64;
  const int E = in_sizes[1];
  const size_t NF = (size_t)N * 64;
  const int NB1 = (N + 1023) / 1024;

  float* ws = (float*)d_ws;
  float* hn = ws;             // current node features (f32)
  float* zb = hn + NF;        // hn + agg
  float* z1 = zb + NF;        // also reused for t
  float* z2 = z1 + NF;
  __hip_bfloat16* hnb = (__hip_bfloat16*)(z2 + NF);  // bf16 mirror of hn
  __hip_bfloat16* P1  = hnb + NF;
  __hip_bfloat16* P2  = P1 + NF;
  int* eidx     = (int*)(P2 + NF);
  int* rowstart = eidx + E;            // N+1 (padded)
  int* cursor   = rowstart + (N + 64);
  int* partials = cursor + (N + 64);   // 64
  int* deg      = partials + 64;
  float* stats  = (float*)(deg + (N + 64));  // 9 slots x [sum(64), sumsq(64)]

  size_t need = (size_t)((char*)(stats + 9 * 128) - (char*)d_ws);
  if (need > ws_size) return;

  // zero deg + stats in one async memset (graph-capture safe)
  hipMemsetAsync(deg, 0, ((size_t)(N + 64) + 9 * 128) * sizeof(int), stream);

  const int gemmBlocks = (N + 31) / 32;
  const int edgeBlocks = (int)(((size_t)E * 8 + 255) / 256);

  // embedding: hn = h @ emb_W + emb_b  (+ bf16 mirror)
  gemm64_kernel<<<gemmBlocks, 256, 0, stream>>>(h, emb_W, emb_b, nullptr, nullptr,
                                                nullptr, hn, nullptr, hnb, N);
  // CSR build (by dst)
  hist_kernel<<<1024, 256, 0, stream>>>(dst, deg, E);
  scan1_kernel<<<NB1, 256, 0, stream>>>(deg, rowstart, partials, N);
  scan2_kernel<<<1, 64, 0, stream>>>(partials, rowstart + N, NB1);
  scan3_kernel<<<NB1, 256, 0, stream>>>(partials, rowstart, cursor, N);
  fill_kernel<<<1024, 256, 0, stream>>>(src, dst, cursor, eidx, E);

  // layer-0 edge rep scoring
  proj_kernel<<<gemmBlocks, 256, 0, stream>>>(hn, pred_W1, pred_b1, P1, P2, N);
  edge_score_kernel<<<edgeBlocks, 256, 0, stream>>>((const ushort*)P1, (const ushort*)P2,
                                                    src, dst, pred_W2, pred_b2,
                                                    (float*)d_out, E, 1);

  for (int i = 0; i < 3; ++i) {
    float* st1 = stats + (size_t)(3 * i + 0) * 128;
    float* st2 = stats + (size_t)(3 * i + 1) * 128;
    float* st3 = stats + (size_t)(3 * i + 2) * 128;
    // z = hn + segment_sum(hn[src], dst)  (bf16 neighbor gather)
    agg_kernel<<<(N + 3) / 4, 256, 0, stream>>>(hn, (const ushort*)hnb, rowstart,
                                                eidx, zb, N);
    // z1 = z @ W1 + b1  (+ stats of z1)
    gemm64_kernel<<<gemmBlocks, 256, 0, stream>>>(zb, mlp_W1 + (size_t)i * 4096,
                                                  mlp_b1 + i * 64, nullptr, nullptr,
                                                  nullptr, z1, st1, nullptr, N);
    // z2 = relu(bn(z1)) @ W2 + b2  (+ stats of z2)
    gemm64_kernel<<<gemmBlocks, 256, 0, stream>>>(z1, mlp_W2 + (size_t)i * 4096,
                                                  mlp_b2 + i * 64, st1,
                                                  mlp_bn_g + i * 64, mlp_bn_b + i * 64,
                                                  z2, st2, nullptr, N);
    // t = relu(bn_apply(z2))  (+ stats of t), t stored in z1 buffer
    bnrelu_kernel<<<784, 256, 0, stream>>>(z2, st2, apply_bn_g + i * 64,
                                           apply_bn_b + i * 64, z1, st3, nullptr, N);
    // hn = relu(bn_out(t))  (+ bf16 mirror for next agg)
    bnrelu_kernel<<<784, 256, 0, stream>>>(z1, st3, out_bn_g + i * 64,
                                           out_bn_b + i * 64, hn, nullptr, hnb, N);
    // edge rep (i+1) scoring
    proj_kernel<<<gemmBlocks, 256, 0, stream>>>(hn, pred_W1 + (size_t)(i + 1) * 8192,
                                                pred_b1 + (i + 1) * 64, P1, P2, N);
    edge_score_kernel<<<edgeBlocks, 256, 0, stream>>>((const ushort*)P1, (const ushort*)P2,
                                                      src, dst,
                                                      pred_W2 + (i + 1) * 128,
                                                      pred_b2 + (i + 1) * 2,
                                                      (float*)d_out, E, 0);
  }
}

// Round 5
// 928.145 us; speedup vs baseline: 1.3152x; 1.1140x over previous
//
#include <hip/hip_runtime.h>
#include <hip/hip_bf16.h>

// ---------------------------------------------------------------------------
// GINEdge: 3-layer GIN (sum agg) + per-layer edge MLP scoring.
//   relu([h_s,h_d]@W1+b1)@W2 == relu(P1[s]+P2[d])@W2,
//   P1 = h@W1[:64] + b1, P2 = h@W1[64:]  (per-node projections).
// R4 changes vs R3:
//   - agg: 8-wide batched neighbor gathers (memory-level parallelism).
//   - edge scoring in CSR (dst-major) order: P2[dst] loaded once per node,
//     only P1[src] gathered per edge; scatter to out[eord].
//   - bn_out+relu fused into agg/proj as per-feature affine (drops 2nd bnrelu).
// Gather payloads (P1/P2, neighbor c) bf16; all accumulation f32.
// ---------------------------------------------------------------------------

#define BN_EPS 1e-5f

static __device__ __forceinline__ float bf2f(ushort u) {
  return __uint_as_float(((unsigned)u) << 16);
}

__global__ __launch_bounds__(256) void hist_kernel(const int* __restrict__ dst,
                                                   int* __restrict__ deg, int E) {
  int i = blockIdx.x * blockDim.x + threadIdx.x;
  int stride = gridDim.x * blockDim.x;
  for (; i < E; i += stride) atomicAdd(&deg[dst[i]], 1);
}

// hierarchical scan, step 1: per-block (1024 elems) exclusive scan + block sum
__global__ __launch_bounds__(256) void scan1_kernel(const int* __restrict__ deg,
                                                    int* __restrict__ rowstart,
                                                    int* __restrict__ partials, int N) {
  __shared__ int wsum[4];
  int tid = threadIdx.x;
  int lane = tid & 63, w = tid >> 6;
  int base = blockIdx.x * 1024 + tid * 4;
  int d0 = 0, d1 = 0, d2 = 0, d3 = 0;
  if (base + 3 < N) {
    int4 v = *reinterpret_cast<const int4*>(deg + base);
    d0 = v.x; d1 = v.y; d2 = v.z; d3 = v.w;
  } else {
    if (base + 0 < N) d0 = deg[base + 0];
    if (base + 1 < N) d1 = deg[base + 1];
    if (base + 2 < N) d2 = deg[base + 2];
  }
  int t0 = d0, t1 = t0 + d1, t2 = t1 + d2, t3 = t2 + d3;
  int tot = t3;
  int inc = tot;
#pragma unroll
  for (int off = 1; off < 64; off <<= 1) {
    int v = __shfl_up(inc, off);
    if (lane >= off) inc += v;
  }
  if (lane == 63) wsum[w] = inc;
  __syncthreads();
  int woff = 0;
  for (int k = 0; k < w; ++k) woff += wsum[k];
  int excl = woff + inc - tot;
  if (base + 0 < N) rowstart[base + 0] = excl;
  if (base + 1 < N) rowstart[base + 1] = excl + t0;
  if (base + 2 < N) rowstart[base + 2] = excl + t1;
  if (base + 3 < N) rowstart[base + 3] = excl + t2;
  if (tid == 255) partials[blockIdx.x] = excl + t3;
}

// step 2: exclusive-scan the (<=64) block partials; write total to rowstart[N]
__global__ __launch_bounds__(64) void scan2_kernel(int* __restrict__ partials,
                                                   int* __restrict__ rowstart_end,
                                                   int NB) {
  int lane = threadIdx.x;
  int v = (lane < NB) ? partials[lane] : 0;
  int inc = v;
#pragma unroll
  for (int off = 1; off < 64; off <<= 1) {
    int t = __shfl_up(inc, off);
    if (lane >= off) inc += t;
  }
  if (lane < NB) partials[lane] = inc - v;
  if (lane == 63) *rowstart_end = inc;
}

// step 3: add block offsets, mirror into cursor
__global__ __launch_bounds__(256) void scan3_kernel(const int* __restrict__ partials,
                                                    int* __restrict__ rowstart,
                                                    int* __restrict__ cursor, int N) {
  int off = partials[blockIdx.x];
  int base = blockIdx.x * 1024 + threadIdx.x * 4;
#pragma unroll
  for (int k = 0; k < 4; ++k) {
    int i = base + k;
    if (i < N) {
      int r = rowstart[i] + off;
      rowstart[i] = r;
      cursor[i] = r;
    }
  }
}

__global__ __launch_bounds__(256) void fill_kernel(const int* __restrict__ src,
                                                   const int* __restrict__ dst,
                                                   int* __restrict__ cursor,
                                                   int* __restrict__ eidx,
                                                   int* __restrict__ eord, int E) {
  int i = blockIdx.x * blockDim.x + threadIdx.x;
  int stride = gridDim.x * blockDim.x;
  for (; i < E; i += stride) {
    int p = atomicAdd(&cursor[dst[i]], 1);
    eidx[p] = src[i];
    eord[p] = i;
  }
}

// z[v] = T(c[v]) + sum_{u->v} T(cb[u]); T = identity (TR=0) or relu-affine
// (TR=1, bn_out fused). 1 wave/node, 8-wide batched gathers.
template <int TR>
__global__ __launch_bounds__(256) void agg_kernel(
    const float* __restrict__ c, const ushort* __restrict__ cb,
    const int* __restrict__ rowstart, const int* __restrict__ eidx,
    const float* __restrict__ stats_in, const float* __restrict__ g_in,
    const float* __restrict__ b_in, float* __restrict__ z, int N) {
  int lane = threadIdx.x & 63;
  int v = blockIdx.x * 4 + (threadIdx.x >> 6);
  if (v >= N) return;
  float sc = 1.f, sh = 0.f;
  if (TR) {
    float invN = 1.0f / (float)N;
    float m = stats_in[lane] * invN;
    float var = stats_in[64 + lane] * invN - m * m;
    sc = g_in[lane] * rsqrtf(var + BN_EPS);
    sh = b_in[lane] - m * sc;
  }
  float x0 = c[(size_t)v * 64 + lane];
  float acc = TR ? fmaxf(x0 * sc + sh, 0.f) : x0;
  int p = rowstart[v], pe = rowstart[v + 1];
  for (; p + 8 <= pe; p += 8) {
    int u[8];
#pragma unroll
    for (int k = 0; k < 8; ++k) u[k] = eidx[p + k];
    float x[8];
#pragma unroll
    for (int k = 0; k < 8; ++k) x[k] = bf2f(cb[(size_t)u[k] * 64 + lane]);
#pragma unroll
    for (int k = 0; k < 8; ++k) acc += TR ? fmaxf(x[k] * sc + sh, 0.f) : x[k];
  }
  if (p + 4 <= pe) {
    int u[4];
#pragma unroll
    for (int k = 0; k < 4; ++k) u[k] = eidx[p + k];
#pragma unroll
    for (int k = 0; k < 4; ++k) {
      float x = bf2f(cb[(size_t)u[k] * 64 + lane]);
      acc += TR ? fmaxf(x * sc + sh, 0.f) : x;
    }
    p += 4;
  }
  for (; p < pe; ++p) {
    float x = bf2f(cb[(size_t)eidx[p] * 64 + lane]);
    acc += TR ? fmaxf(x * sc + sh, 0.f) : x;
  }
  z[(size_t)v * 64 + lane] = acc;
}

// out[n][f] = bias[f] + sum_k T(in[n][k]) * W[k][f]
// T = identity, or (if stats_in) relu(bn(x)). Optional col sum/sumsq of out
// into stats_out; optional bf16 mirror of out into out_bf.
__global__ __launch_bounds__(256) void gemm64_kernel(
    const float* __restrict__ in, const float* __restrict__ W,
    const float* __restrict__ bias, const float* __restrict__ stats_in,
    const float* __restrict__ g_in, const float* __restrict__ b_in,
    float* __restrict__ out, float* __restrict__ stats_out,
    __hip_bfloat16* __restrict__ out_bf, int N) {
  __shared__ float sW[64][64];
  __shared__ float sx[32][64];
  __shared__ float red[2][4][64];
  int tid = threadIdx.x;
  int lane = tid & 63, w = tid >> 6;
  int n0 = blockIdx.x * 32;
#pragma unroll
  for (int r = 0; r < 16; ++r) {
    int idx = r * 256 + tid;
    sW[idx >> 6][idx & 63] = W[idx];
  }
  float sc = 1.f, sh = 0.f;
  if (stats_in) {
    float invN = 1.0f / (float)N;
    float m = stats_in[lane] * invN;
    float var = stats_in[64 + lane] * invN - m * m;
    sc = g_in[lane] * rsqrtf(var + BN_EPS);
    sh = b_in[lane] - m * sc;
  }
#pragma unroll
  for (int r = 0; r < 8; ++r) {
    int idx = r * 256 + tid;  // (idx&63)==lane since 256%64==0
    int n = n0 + (idx >> 6);
    float x = (n < N) ? in[(size_t)n * 64 + lane] : 0.f;
    if (stats_in) x = fmaxf(x * sc + sh, 0.f);
    sx[idx >> 6][lane] = x;
  }
  __syncthreads();
  float acc[8];
  float bz = bias ? bias[lane] : 0.f;
#pragma unroll
  for (int j = 0; j < 8; ++j) acc[j] = bz;
  for (int k = 0; k < 64; ++k) {
    float wv = sW[k][lane];
#pragma unroll
    for (int j = 0; j < 8; ++j) acc[j] = fmaf(sx[w * 8 + j][k], wv, acc[j]);
  }
  float ps = 0.f, pq = 0.f;
#pragma unroll
  for (int j = 0; j < 8; ++j) {
    int n = n0 + w * 8 + j;
    if (n < N) {
      out[(size_t)n * 64 + lane] = acc[j];
      if (out_bf) out_bf[(size_t)n * 64 + lane] = __float2bfloat16(acc[j]);
      ps += acc[j];
      pq += acc[j] * acc[j];
    }
  }
  if (stats_out) {
    red[0][w][lane] = ps;
    red[1][w][lane] = pq;
    __syncthreads();
    if (w == 0) {
      float s = red[0][0][lane] + red[0][1][lane] + red[0][2][lane] + red[0][3][lane];
      float q = red[1][0][lane] + red[1][1][lane] + red[1][2][lane] + red[1][3][lane];
      atomicAdd(&stats_out[lane], s);
      atomicAdd(&stats_out[64 + lane], q);
    }
  }
}

// P1 = T(c) @ W1[0:64] + b1 ; P2 = T(c) @ W1[64:128]  -> bf16
// T = identity or relu-affine (bn_out fused) per input feature.
__global__ __launch_bounds__(256) void proj_kernel(
    const float* __restrict__ c, const float* __restrict__ W1,
    const float* __restrict__ b1, const float* __restrict__ stats_in,
    const float* __restrict__ g_in, const float* __restrict__ b_in,
    __hip_bfloat16* __restrict__ P1, __hip_bfloat16* __restrict__ P2, int N) {
  __shared__ float sWa[64][64];
  __shared__ float sWb[64][64];
  __shared__ float sx[32][64];
  int tid = threadIdx.x, lane = tid & 63, w = tid >> 6;
  int n0 = blockIdx.x * 32;
#pragma unroll
  for (int r = 0; r < 16; ++r) {
    int idx = r * 256 + tid;
    sWa[idx >> 6][idx & 63] = W1[idx];
    sWb[idx >> 6][idx & 63] = W1[4096 + idx];
  }
  float sc = 1.f, sh = 0.f;
  if (stats_in) {
    float invN = 1.0f / (float)N;
    float m = stats_in[lane] * invN;
    float var = stats_in[64 + lane] * invN - m * m;
    sc = g_in[lane] * rsqrtf(var + BN_EPS);
    sh = b_in[lane] - m * sc;
  }
#pragma unroll
  for (int r = 0; r < 8; ++r) {
    int idx = r * 256 + tid;
    int n = n0 + (idx >> 6);
    float x = (n < N) ? c[(size_t)n * 64 + lane] : 0.f;
    if (stats_in) x = fmaxf(x * sc + sh, 0.f);
    sx[idx >> 6][lane] = x;
  }
  __syncthreads();
  float a1[8], a2[8];
  float bz = b1[lane];
#pragma unroll
  for (int j = 0; j < 8; ++j) { a1[j] = bz; a2[j] = 0.f; }
  for (int k = 0; k < 64; ++k) {
    float wa = sWa[k][lane];
    float wb = sWb[k][lane];
#pragma unroll
    for (int j = 0; j < 8; ++j) {
      float x = sx[w * 8 + j][k];
      a1[j] = fmaf(x, wa, a1[j]);
      a2[j] = fmaf(x, wb, a2[j]);
    }
  }
#pragma unroll
  for (int j = 0; j < 8; ++j) {
    int n = n0 + w * 8 + j;
    if (n < N) {
      P1[(size_t)n * 64 + lane] = __float2bfloat16(a1[j]);
      P2[(size_t)n * 64 + lane] = __float2bfloat16(a2[j]);
    }
  }
}

// t = relu(bn(in)); col stats of t; bf16 mirror. (apply_bn stage)
__global__ __launch_bounds__(256) void bnrelu_kernel(
    const float* __restrict__ in, const float* __restrict__ stats_in,
    const float* __restrict__ g_in, const float* __restrict__ b_in,
    float* __restrict__ out, float* __restrict__ stats_out,
    __hip_bfloat16* __restrict__ out_bf, int N) {
  __shared__ float red[2][4][64];
  int tid = threadIdx.x;
  int lane = tid & 63, w = tid >> 6;
  float invN = 1.0f / (float)N;
  float m = stats_in[lane] * invN;
  float var = stats_in[64 + lane] * invN - m * m;
  float sc = g_in[lane] * rsqrtf(var + BN_EPS);
  float sh = b_in[lane] - m * sc;
  float ps = 0.f, pq = 0.f;
  int rows_per_grid = gridDim.x * (blockDim.x >> 6);
  for (int n = blockIdx.x * (blockDim.x >> 6) + w; n < N; n += rows_per_grid) {
    float x = fmaxf(in[(size_t)n * 64 + lane] * sc + sh, 0.f);
    out[(size_t)n * 64 + lane] = x;
    if (out_bf) out_bf[(size_t)n * 64 + lane] = __float2bfloat16(x);
    ps += x;
    pq += x * x;
  }
  if (stats_out) {
    red[0][w][lane] = ps;
    red[1][w][lane] = pq;
    __syncthreads();
    if (w == 0) {
      float s = red[0][0][lane] + red[0][1][lane] + red[0][2][lane] + red[0][3][lane];
      float q = red[1][0][lane] + red[1][1][lane] + red[1][2][lane] + red[1][3][lane];
      atomicAdd(&stats_out[lane], s);
      atomicAdd(&stats_out[64 + lane], q);
    }
  }
}

// CSR (dst-major) edge scoring: wave per dst node v. P2[v] held in regs;
// 8 lane-groups each score one edge (gather P1[src] only), scatter to
// out[eord[p]].  score = relu(P1[s]+P2[v]) @ W2 + b2, accumulated over layers.
__global__ __launch_bounds__(256) void edge_score_csr_kernel(
    const ushort* __restrict__ P1, const ushort* __restrict__ P2,
    const int* __restrict__ rowstart, const int* __restrict__ eidx,
    const int* __restrict__ eord, const float* __restrict__ W2,
    const float* __restrict__ b2, float* __restrict__ out, int N, int first) {
  int lane = threadIdx.x & 63;
  int v = blockIdx.x * 4 + (threadIdx.x >> 6);
  if (v >= N) return;
  int sub = lane & 7;   // feature octet within the 64
  int grp = lane >> 3;  // edge slot (8 edges in flight per wave)
  // per-lane W2 block: feats sub*8..sub*8+7 x 2 outputs = 16 consecutive floats
  float w[16];
  const float4* wp = reinterpret_cast<const float4*>(W2 + sub * 16);
#pragma unroll
  for (int k = 0; k < 4; ++k) {
    float4 t = wp[k];
    w[4 * k + 0] = t.x; w[4 * k + 1] = t.y; w[4 * k + 2] = t.z; w[4 * k + 3] = t.w;
  }
  float bb0 = b2[0], bb1 = b2[1];
  uint4 pb = *reinterpret_cast<const uint4*>(P2 + (size_t)v * 64 + sub * 8);
  unsigned bv[4] = {pb.x, pb.y, pb.z, pb.w};
  int p0 = rowstart[v], p1 = rowstart[v + 1];
  for (int p = p0 + grp; p < p1; p += 8) {
    int s = eidx[p];
    int e = eord[p];
    uint4 pa = *reinterpret_cast<const uint4*>(P1 + (size_t)s * 64 + sub * 8);
    unsigned av[4] = {pa.x, pa.y, pa.z, pa.w};
    float q0 = 0.f, q1 = 0.f;
#pragma unroll
    for (int k = 0; k < 4; ++k) {
      float a_lo = __uint_as_float(av[k] << 16);
      float a_hi = __uint_as_float(av[k] & 0xffff0000u);
      float b_lo = __uint_as_float(bv[k] << 16);
      float b_hi = __uint_as_float(bv[k] & 0xffff0000u);
      float v0 = fmaxf(a_lo + b_lo, 0.f);
      float v1 = fmaxf(a_hi + b_hi, 0.f);
      q0 = fmaf(v0, w[4 * k + 0], fmaf(v1, w[4 * k + 2], q0));
      q1 = fmaf(v0, w[4 * k + 1], fmaf(v1, w[4 * k + 3], q1));
    }
    // reduce over the 8 lanes of this group (masks 1,2,4 stay in-group)
#pragma unroll
    for (int mm = 1; mm < 8; mm <<= 1) {
      q0 += __shfl_xor(q0, mm);
      q1 += __shfl_xor(q1, mm);
    }
    if (sub == 0) {
      float o0 = q0 + bb0, o1 = q1 + bb1;
      if (!first) {
        o0 += out[(size_t)e * 2];
        o1 += out[(size_t)e * 2 + 1];
      }
      out[(size_t)e * 2] = o0;
      out[(size_t)e * 2 + 1] = o1;
    }
  }
}

extern "C" void kernel_launch(void* const* d_in, const int* in_sizes, int n_in,
                              void* d_out, int out_size, void* d_ws, size_t ws_size,
                              hipStream_t stream) {
  const float* h          = (const float*)d_in[0];
  const int*   src        = (const int*)d_in[1];
  const int*   dst        = (const int*)d_in[2];
  const float* emb_W      = (const float*)d_in[3];
  const float* emb_b      = (const float*)d_in[4];
  const float* mlp_W1     = (const float*)d_in[5];
  const float* mlp_b1     = (const float*)d_in[6];
  const float* mlp_bn_g   = (const float*)d_in[7];
  const float* mlp_bn_b   = (const float*)d_in[8];
  const float* mlp_W2     = (const float*)d_in[9];
  const float* mlp_b2     = (const float*)d_in[10];
  const float* apply_bn_g = (const float*)d_in[11];
  const float* apply_bn_b = (const float*)d_in[12];
  const float* out_bn_g   = (const float*)d_in[13];
  const float* out_bn_b   = (const float*)d_in[14];
  const float* pred_W1    = (const float*)d_in[15];
  const float* pred_b1    = (const float*)d_in[16];
  const float* pred_W2    = (const float*)d_in[17];
  const float* pred_b2    = (const float*)d_in[18];

  const int N = in_sizes[0] / 64;
  const int E = in_sizes[1];
  const size_t NF = (size_t)N * 64;
  const int NB1 = (N + 1023) / 1024;

  float* ws = (float*)d_ws;
  float* c  = ws;             // current node features (f32), pre-bn_out
  float* zb = c + NF;         // agg output
  float* z1 = zb + NF;
  float* z2 = z1 + NF;
  __hip_bfloat16* cb = (__hip_bfloat16*)(z2 + NF);  // bf16 mirror of c
  __hip_bfloat16* P1 = cb + NF;
  __hip_bfloat16* P2 = P1 + NF;
  int* eidx     = (int*)(P2 + NF);
  int* eord     = eidx + E;
  int* rowstart = eord + E;            // N+1 (padded)
  int* cursor   = rowstart + (N + 64);
  int* partials = cursor + (N + 64);   // 64
  int* deg      = partials + 64;
  float* stats  = (float*)(deg + (N + 64));  // 9 slots x [sum(64), sumsq(64)]

  size_t need = (size_t)((char*)(stats + 9 * 128) - (char*)d_ws);
  if (need > ws_size) return;

  // zero deg + stats in one async memset (graph-capture safe)
  hipMemsetAsync(deg, 0, ((size_t)(N + 64) + 9 * 128) * sizeof(int), stream);

  const int gemmBlocks = (N + 31) / 32;
  const int nodeBlocks = (N + 3) / 4;

  // embedding: c = h @ emb_W + emb_b  (+ bf16 mirror)
  gemm64_kernel<<<gemmBlocks, 256, 0, stream>>>(h, emb_W, emb_b, nullptr, nullptr,
                                                nullptr, c, nullptr, cb, N);
  // CSR build (by dst), with original edge ids
  hist_kernel<<<1024, 256, 0, stream>>>(dst, deg, E);
  scan1_kernel<<<NB1, 256, 0, stream>>>(deg, rowstart, partials, N);
  scan2_kernel<<<1, 64, 0, stream>>>(partials, rowstart + N, NB1);
  scan3_kernel<<<NB1, 256, 0, stream>>>(partials, rowstart, cursor, N);
  fill_kernel<<<1024, 256, 0, stream>>>(src, dst, cursor, eidx, eord, E);

  // edge rep 0 scoring (identity transform)
  proj_kernel<<<gemmBlocks, 256, 0, stream>>>(c, pred_W1, pred_b1, nullptr, nullptr,
                                              nullptr, P1, P2, N);
  edge_score_csr_kernel<<<nodeBlocks, 256, 0, stream>>>(
      (const ushort*)P1, (const ushort*)P2, rowstart, eidx, eord, pred_W2, pred_b2,
      (float*)d_out, N, 1);

  for (int i = 0; i < 3; ++i) {
    float* st1 = stats + (size_t)(3 * i + 0) * 128;
    float* st2 = stats + (size_t)(3 * i + 1) * 128;
    float* st3 = stats + (size_t)(3 * i + 2) * 128;
    const float* stP = (i == 0) ? nullptr : stats + (size_t)(3 * (i - 1) + 2) * 128;
    const float* gP  = (i == 0) ? nullptr : out_bn_g + (i - 1) * 64;
    const float* bP  = (i == 0) ? nullptr : out_bn_b + (i - 1) * 64;

    // zb = T(c) + segment_sum(T(c)[src], dst); T = pending bn_out (or id)
    if (i == 0)
      agg_kernel<0><<<nodeBlocks, 256, 0, stream>>>(c, (const ushort*)cb, rowstart,
                                                    eidx, nullptr, nullptr, nullptr,
                                                    zb, N);
    else
      agg_kernel<1><<<nodeBlocks, 256, 0, stream>>>(c, (const ushort*)cb, rowstart,
                                                    eidx, stP, gP, bP, zb, N);
    // z1 = zb @ W1 + b1  (+ stats)
    gemm64_kernel<<<gemmBlocks, 256, 0, stream>>>(zb, mlp_W1 + (size_t)i * 4096,
                                                  mlp_b1 + i * 64, nullptr, nullptr,
                                                  nullptr, z1, st1, nullptr, N);
    // z2 = relu(bn_mlp(z1)) @ W2 + b2  (+ stats)
    gemm64_kernel<<<gemmBlocks, 256, 0, stream>>>(z1, mlp_W2 + (size_t)i * 4096,
                                                  mlp_b2 + i * 64, st1,
                                                  mlp_bn_g + i * 64, mlp_bn_b + i * 64,
                                                  z2, st2, nullptr, N);
    // c = relu(bn_apply(z2))  (+ stats st3, bf16 mirror); bn_out deferred
    bnrelu_kernel<<<784, 256, 0, stream>>>(z2, st2, apply_bn_g + i * 64,
                                           apply_bn_b + i * 64, c, st3, cb, N);
    // edge rep (i+1): proj applies deferred bn_out[i] via st3
    proj_kernel<<<gemmBlocks, 256, 0, stream>>>(c, pred_W1 + (size_t)(i + 1) * 8192,
                                                pred_b1 + (i + 1) * 64, st3,
                                                out_bn_g + i * 64, out_bn_b + i * 64,
                                                P1, P2, N);
    edge_score_csr_kernel<<<nodeBlocks, 256, 0, stream>>>(
        (const ushort*)P1, (const ushort*)P2, rowstart, eidx, eord,
        pred_W2 + (i + 1) * 128, pred_b2 + (i + 1) * 2, (float*)d_out, N, 0);
  }
}